// Round 7
// baseline (121.794 us; speedup 1.0000x reference)
//
#include <hip/hip_runtime.h>
#include <hip/hip_fp16.h>

// ---------------------------------------------------------------------------
// ROUND 14: dense-MFMA sim. Sparse paradigm floor ~20us (DS-issue + barriers
// on 4 CUs); non-kernel floor ~55us (harness ws-poison fill, launch-count-
// independent). Rewrite sim as per-column 64x64 dense evolution:
//   S[m][n] (m = wires0-5 = flat bits 11..6, n = wires6-11 = bits 5..0)
//   layer: S <- P_cnot ( L S R^T ),  L = g0x..xg5, R = g6x..xg11
//   P_cnot (src = gray12(dst)) folds COMPLETELY into operand addressing:
//     S'[m][n] = sum_k L[gray6(m)][k] * U_{x(m)}[k][n],  x = 1 even m, 2 odd
//     U1[k][n] = sum_j S[k][j] R[gray6(n)][j]   (mfma: A=S, B^T=R'-rows)
//     U2[k][n] = U1[k][n^63]                    (free row-flip A-read, since
//                                                gray6(63)=32)
//   Step2 computed TRANSPOSED: W[n][m] = sum_k U^T[n][k] L'^T[k][m]
//     -> mfma A = U^T rows (row-major, built that way), B^T = L rows at
//        gray6(m) (per-lane addr); output C/D col = m (lane) -> parity
//        select W1/W2 per lane; rows = n-runs of 4 -> row-major S' b64 writes.
// One wave per block (4 blocks, 1 column each): no multi-wave barriers;
// f16 operands + f32 MFMA accumulation (2 roundings/layer vs 12 before).
// mfma_f32_32x32x16_f16: A[m][k]: m=lane&31, k=8*(lane>>5)+i (consecutive
// f16 = consecutive k); B[k][n]: n=lane&31, same k split; C/D (HW-verified
// m74/m101): col=lane&31, row=(reg&3)+8*(reg>>2)+4*(lane>>5).
// All f16 [64][64] planes XOR-swizzled per 16B unit: unit ^= (row&7)
// (G4: breaks the 128B-row-stride bank conflict on ds_read_b128).
// Gate convention (verified R7-R13): Rot = [[A-iB, -C-iD],[C-iD, A+iB]],
// A=ca*ch B=sa*ch C=cb*sh D=sb*sh. Column b basis = flat b<<10 -> S0 =
// delta(m=16b, n=0). finish_kernel (verified R8+) unchanged.
// ---------------------------------------------------------------------------

typedef __half2 h2;
typedef _Float16 f16;
typedef __attribute__((ext_vector_type(8))) _Float16 f16x8;
typedef __attribute__((ext_vector_type(16))) float f32x16;

struct Gate32 { float a, b, c, d; };

#define SGN2 0x80008000
#define Z16 f32x16{0,0,0,0,0,0,0,0,0,0,0,0,0,0,0,0}

__device__ __forceinline__ float bpermf(int addr4, float v) {
    return __int_as_float(__builtin_amdgcn_ds_bpermute(addr4, __float_as_int(v)));
}
__device__ __forceinline__ int bci(h2 v)  { return __builtin_bit_cast(int, v); }
__device__ __forceinline__ h2 bch2(int v) { return __builtin_bit_cast(h2, v); }
__device__ __forceinline__ int g6(int x)  { return (x ^ (x >> 1)) & 63; }
__device__ __forceinline__ int moff(int row, int unit) {       // byte off in
    return row * 128 + ((unit ^ (row & 7)) << 4);              // f16[64][64]
}
__device__ __forceinline__ f16x8 fneg8(f16x8 v) {
    int4 x = __builtin_bit_cast(int4, v);
    x.x ^= SGN2; x.y ^= SGN2; x.z ^= SGN2; x.w ^= SGN2;
    return __builtin_bit_cast(f16x8, x);
}
__device__ __forceinline__ f32x16 MFMA(f16x8 a, f16x8 b, f32x16 c) {
    return __builtin_amdgcn_mfma_f32_32x32x16_f16(a, b, c, 0, 0, 0);
}

struct C2 { float r, i; };
__device__ __forceinline__ C2 cmul(C2 x, C2 y) {
    return { x.r*y.r - x.i*y.i, x.r*y.i + x.i*y.r };
}
// Rot entry (bi,bj): [[A-iB, -C-iD],[C-iD, A+iB]]
__device__ __forceinline__ C2 gent(const Gate32 g, int bi, int bj) {
    const float re = (bi == bj) ? g.a : (bi ? g.c : -g.c);
    const float im = (bi == bj) ? (bi ? g.b : -g.b) : -g.d;
    return { re, im };
}

// ---- kernel 0: gate coefficient table (R8-verified) -----------------------
__global__ void coeff_kernel(const float* __restrict__ wts, Gate32* __restrict__ tbl) {
    const int g = threadIdx.x;
    if (g >= 96) return;
    const int l = g / 12, w = g % 12;
    const float* lw = wts + l*36 + w*3;
    float ch, sh, ca, sa, cb, sb;
    __sincosf(0.5f*lw[1],           &sh, &ch);
    __sincosf(0.5f*(lw[0]+lw[2]),   &sa, &ca);
    __sincosf(0.5f*(lw[0]-lw[2]),   &sb, &cb);
    Gate32 r; r.a = ca*ch; r.b = sa*ch; r.c = cb*sh; r.d = sb*sh;
    tbl[g] = r;
}

// ---- kernel 1: 4 blocks x 1 wave, dense MFMA column sim -------------------
__global__ __launch_bounds__(64, 1)
void sim_kernel(const Gate32* __restrict__ tbl, float2* __restrict__ cols) {
    extern __shared__ char smem[];
    char* Lr = smem;                 // f16[64][64] planes, unit-swizzled
    char* Li = smem + 8192;
    char* Rr = smem + 16384;
    char* Ri = smem + 24576;
    char* Sr = smem + 32768;         // state planes (row-major [m][n])
    char* Si = smem + 40960;
    char* Ur = smem + 49152;         // U^T planes (row-major [n][m''])
    char* Ui = smem + 57344;
    float* KLr = (float*)(smem + 65536);   // 8x8 factor matrices
    float* KLi = KLr + 64;  float* KRr = KLr + 128; float* KRi = KLr + 192;
    f16* KLpr = (f16*)(KLr + 256);
    f16* KLpi = KLpr + 64;  f16* KRpr = KLpr + 128; f16* KRpi = KLpr + 192;

    const int lane = threadIdx.x;
    const int b    = blockIdx.x;
    const int lo5  = lane & 31, hi = lane >> 5;

    // ---- init S = delta(m = 16b, n = 0) ----
    {
        const int4 z = make_int4(0, 0, 0, 0);
#pragma unroll
        for (int u = 0; u < 8; ++u) {
            const int idx = u * 64 + lane;          // 512 units per plane
            const int row = idx >> 3, un = idx & 7;
            *(int4*)(Sr + moff(row, un)) = z;
            *(int4*)(Si + moff(row, un)) = z;
        }
    }
    __syncthreads();
    if (lane == 0) {
        const int row = 16 * b;
        *(f16*)(Sr + moff(row, 0)) = (f16)1.0f;     // element (row, col 0)
    }
    __syncthreads();

#pragma unroll 1
    for (int l = 0; l < 8; ++l) {
        const Gate32* gl = tbl + l * 12;
        // ---- build 8x8 Kronecker halves: lane = entry (ip, jp) ----
        {
            const int ip = lane >> 3, jp = lane & 7;
            const int i2 = (ip>>2)&1, i1 = (ip>>1)&1, i0 = ip&1;
            const int j2 = (jp>>2)&1, j1 = (jp>>1)&1, j0 = jp&1;
            const C2 kl  = cmul(cmul(gent(gl[0],i2,j2), gent(gl[1],i1,j1)), gent(gl[2],i0,j0));
            const C2 klp = cmul(cmul(gent(gl[3],i2,j2), gent(gl[4],i1,j1)), gent(gl[5],i0,j0));
            const C2 kr  = cmul(cmul(gent(gl[6],i2,j2), gent(gl[7],i1,j1)), gent(gl[8],i0,j0));
            const C2 krp = cmul(cmul(gent(gl[9],i2,j2), gent(gl[10],i1,j1)), gent(gl[11],i0,j0));
            KLr[lane] = kl.r;  KLi[lane] = kl.i;
            KRr[lane] = kr.r;  KRi[lane] = kr.i;
            KLpr[lane] = (f16)klp.r;  KLpi[lane] = (f16)klp.i;
            KRpr[lane] = (f16)krp.r;  KRpi[lane] = (f16)krp.i;
        }
        __syncthreads();
        // ---- row build: lane = row r of L and of R (outer product) ----
        {
            const int r = lane, rh = r >> 3, rl = r & 7;
#pragma unroll
            for (int side = 0; side < 2; ++side) {
                const float* xr4 = side ? (KRr + rh*8) : (KLr + rh*8);
                const float* xi4 = side ? (KRi + rh*8) : (KLi + rh*8);
                const int4 pyr = *(const int4*)((side ? KRpr : KLpr) + rl*8);
                const int4 pyi = *(const int4*)((side ? KRpi : KLpi) + rl*8);
                const h2 yr[4] = { bch2(pyr.x), bch2(pyr.y), bch2(pyr.z), bch2(pyr.w) };
                const h2 yi[4] = { bch2(pyi.x), bch2(pyi.y), bch2(pyi.z), bch2(pyi.w) };
                char* Pr = side ? Rr : Lr;
                char* Pi = side ? Ri : Li;
#pragma unroll
                for (int hk = 0; hk < 8; ++hk) {
                    const h2 xr2  = __float2half2_rn(xr4[hk]);
                    const h2 xi2  = __float2half2_rn(xi4[hk]);
                    const h2 nxi2 = bch2(bci(xi2) ^ SGN2);
                    h2 oR[4], oI[4];
#pragma unroll
                    for (int t = 0; t < 4; ++t) {
                        oR[t] = __hfma2(nxi2, yi[t], __hmul2(xr2, yr[t]));
                        oI[t] = __hfma2(xi2,  yr[t], __hmul2(xr2, yi[t]));
                    }
                    *(int4*)(Pr + moff(r, hk)) = make_int4(bci(oR[0]), bci(oR[1]), bci(oR[2]), bci(oR[3]));
                    *(int4*)(Pi + moff(r, hk)) = make_int4(bci(oI[0]), bci(oI[1]), bci(oI[2]), bci(oI[3]));
                }
            }
        }
        __syncthreads();
        // ---- step 1: U = S . R'^T   (R' rows = gray6-read) ----
#pragma unroll
        for (int mt = 0; mt < 2; ++mt)
#pragma unroll
        for (int nt = 0; nt < 2; ++nt) {
            f16x8 asr[4], asi[4], brr[4], bri[4];
            const int arow = 32*mt + lo5;
            const int brow = g6(32*nt + lo5);
#pragma unroll
            for (int kc = 0; kc < 4; ++kc) {
                const int un = 2*kc + hi;
                asr[kc] = *(const f16x8*)(Sr + moff(arow, un));
                asi[kc] = *(const f16x8*)(Si + moff(arow, un));
                brr[kc] = *(const f16x8*)(Rr + moff(brow, un));
                bri[kc] = *(const f16x8*)(Ri + moff(brow, un));
            }
            f32x16 ur = Z16, ui = Z16;
#pragma unroll
            for (int kc = 0; kc < 4; ++kc) {
                const f16x8 nri = fneg8(bri[kc]);
                ur = MFMA(asr[kc], brr[kc], ur);   // Ur = Sr.Rr^T - Si.Ri^T
                ur = MFMA(asi[kc], nri,     ur);
                ui = MFMA(asr[kc], bri[kc], ui);   // Ui = Sr.Ri^T + Si.Rr^T
                ui = MFMA(asi[kc], brr[kc], ui);
            }
            // write U^T[n][m]: lane col n, 4-runs of consecutive m
            const int urow = 32*nt + lo5;
#pragma unroll
            for (int gg = 0; gg < 4; ++gg) {
                const h2 p0 = __floats2half2_rn(ur[4*gg+0], ur[4*gg+1]);
                const h2 p1 = __floats2half2_rn(ur[4*gg+2], ur[4*gg+3]);
                *(int2*)(Ur + moff(urow, 4*mt+gg) + 8*hi) = make_int2(bci(p0), bci(p1));
                const h2 q0 = __floats2half2_rn(ui[4*gg+0], ui[4*gg+1]);
                const h2 q1 = __floats2half2_rn(ui[4*gg+2], ui[4*gg+3]);
                *(int2*)(Ui + moff(urow, 4*mt+gg) + 8*hi) = make_int2(bci(q0), bci(q1));
            }
        }
        __syncthreads();
        // ---- step 2: W[n][m] = U^T . L'^T;  parity-select W1/W2 per m ----
#pragma unroll
        for (int nt2 = 0; nt2 < 2; ++nt2) {
            f16x8 a1r[4], a1i[4], a2r[4], a2i[4];
            const int r1 = 32*nt2 + lo5, r2 = r1 ^ 63;   // U2 = row-flip read
#pragma unroll
            for (int kc = 0; kc < 4; ++kc) {
                const int un = 2*kc + hi;
                a1r[kc] = *(const f16x8*)(Ur + moff(r1, un));
                a1i[kc] = *(const f16x8*)(Ui + moff(r1, un));
                a2r[kc] = *(const f16x8*)(Ur + moff(r2, un));
                a2i[kc] = *(const f16x8*)(Ui + moff(r2, un));
            }
#pragma unroll
            for (int mt2 = 0; mt2 < 2; ++mt2) {
                const int m = 32*mt2 + lo5;
                const int lrow = g6(m);                  // folded row-gray
                f16x8 blr[4], bli[4];
#pragma unroll
                for (int kc = 0; kc < 4; ++kc) {
                    const int un = 2*kc + hi;
                    blr[kc] = *(const f16x8*)(Lr + moff(lrow, un));
                    bli[kc] = *(const f16x8*)(Li + moff(lrow, un));
                }
                f32x16 w1r = Z16, w1i = Z16, w2r = Z16, w2i = Z16;
#pragma unroll
                for (int kc = 0; kc < 4; ++kc) {
                    const f16x8 nbli = fneg8(bli[kc]);
                    w1r = MFMA(a1r[kc], blr[kc], w1r);
                    w1r = MFMA(a1i[kc], nbli,    w1r);
                    w1i = MFMA(a1r[kc], bli[kc], w1i);
                    w1i = MFMA(a1i[kc], blr[kc], w1i);
                    w2r = MFMA(a2r[kc], blr[kc], w2r);
                    w2r = MFMA(a2i[kc], nbli,    w2r);
                    w2i = MFMA(a2r[kc], bli[kc], w2i);
                    w2i = MFMA(a2i[kc], blr[kc], w2i);
                }
                const bool odd = (m & 1);
                if (l < 7) {                             // S'[m][n] row-major
#pragma unroll
                    for (int gg = 0; gg < 4; ++gg) {
                        float s0 = odd ? w2r[4*gg+0] : w1r[4*gg+0];
                        float s1 = odd ? w2r[4*gg+1] : w1r[4*gg+1];
                        float s2 = odd ? w2r[4*gg+2] : w1r[4*gg+2];
                        float s3 = odd ? w2r[4*gg+3] : w1r[4*gg+3];
                        *(int2*)(Sr + moff(m, 4*nt2+gg) + 8*hi) =
                            make_int2(bci(__floats2half2_rn(s0, s1)),
                                      bci(__floats2half2_rn(s2, s3)));
                        s0 = odd ? w2i[4*gg+0] : w1i[4*gg+0];
                        s1 = odd ? w2i[4*gg+1] : w1i[4*gg+1];
                        s2 = odd ? w2i[4*gg+2] : w1i[4*gg+2];
                        s3 = odd ? w2i[4*gg+3] : w1i[4*gg+3];
                        *(int2*)(Si + moff(m, 4*nt2+gg) + 8*hi) =
                            make_int2(bci(__floats2half2_rn(s0, s1)),
                                      bci(__floats2half2_rn(s2, s3)));
                    }
                } else {                                 // final: f32 global
#pragma unroll
                    for (int gg = 0; gg < 4; ++gg)
#pragma unroll
                    for (int e = 0; e < 4; ++e) {
                        const int n = 32*nt2 + 8*gg + 4*hi + e;
                        const int r = 4*gg + e;
                        const float vr = odd ? w2r[r] : w1r[r];
                        const float vi = odd ? w2i[r] : w1i[r];
                        cols[b*4096 + (m << 6) + n] = make_float2(vr, vi);
                    }
                }
            }
        }
        __syncthreads();
    }
}

// ---- kernel 2: redundant G-reduce per block + per-sample quadratic form ---
__global__ __launch_bounds__(256)
void finish_kernel(const float* __restrict__ sb,
                   const float2* __restrict__ cols,
                   const float* __restrict__ hw,
                   const float* __restrict__ hb,
                   float* __restrict__ out, int B) {
    const int tid  = threadIdx.x;
    const int lane = tid & 63, wid = tid >> 6;

    float hwv[12];
#pragma unroll
    for (int w = 0; w < 12; ++w) hwv[w] = hw[w];

    float Klo = 0.f;
#pragma unroll
    for (int w = 4; w < 12; ++w)
        Klo += ((tid >> (11 - w)) & 1) ? -hwv[w] : hwv[w];

    float g[10];
#pragma unroll
    for (int m = 0; m < 10; ++m) g[m] = 0.f;

#pragma unroll 1
    for (int it = 0; it < 16; ++it) {
        const int q = (it << 8) | tid;
        const float2 c0 = cols[q];
        const float2 c1 = cols[4096  + q];
        const float2 c2 = cols[8192  + q];
        const float2 c3 = cols[12288 + q];
        float K = Klo;
#pragma unroll
        for (int w = 0; w < 4; ++w)
            K += ((it >> (3 - w)) & 1) ? -hwv[w] : hwv[w];
        g[0] += K * (c0.x*c0.x + c0.y*c0.y);
        g[1] += K * (c1.x*c1.x + c1.y*c1.y);
        g[2] += K * (c2.x*c2.x + c2.y*c2.y);
        g[3] += K * (c3.x*c3.x + c3.y*c3.y);
        g[4] += K * (c0.x*c1.x + c0.y*c1.y);
        g[5] += K * (c2.x*c3.x + c2.y*c3.y);
        g[6] += K * (c0.x*c2.y - c0.y*c2.x);
        g[7] += K * (c0.x*c3.y - c0.y*c3.x);
        g[8] += K * (c1.x*c2.y - c1.y*c2.x);
        g[9] += K * (c1.x*c3.y - c1.y*c3.x);
    }

    __shared__ float gsh[4][10];
#pragma unroll
    for (int m = 0; m < 10; ++m) {
#pragma unroll
        for (int off = 1; off < 64; off <<= 1)
            g[m] += bpermf((lane ^ off) << 2, g[m]);
    }
    if (lane == 0) {
#pragma unroll
        for (int m = 0; m < 10; ++m) gsh[wid][m] = g[m];
    }
    __syncthreads();
    float G[10];
#pragma unroll
    for (int m = 0; m < 10; ++m) {
        const float s = gsh[0][m] + gsh[1][m] + gsh[2][m] + gsh[3][m];
        G[m] = (m < 4) ? s : 2.f * s;
    }

    const int i = blockIdx.x * 256 + tid;
    if (i < B) {
        const float2 x = *reinterpret_cast<const float2*>(sb + i*8);
        float c0, s0, c1, s1;
        __sincosf(0.5f * x.x, &s0, &c0);
        __sincosf(0.5f * x.y, &s1, &c1);
        const float a0 = c0*c1, a1 = c0*s1, a2 = s0*c1, a3 = s0*s1;
        const float r = G[0]*a0*a0 + G[1]*a1*a1 + G[2]*a2*a2 + G[3]*a3*a3
                      + G[4]*(a0*a1) + G[5]*(a2*a3)
                      + G[6]*(a0*a2) + G[7]*(a0*a3)
                      + G[8]*(a1*a2) + G[9]*(a1*a3);
        out[i] = r + hb[0];
    }
}

extern "C" void kernel_launch(void* const* d_in, const int* in_sizes, int n_in,
                              void* d_out, int out_size, void* d_ws, size_t ws_size,
                              hipStream_t stream) {
    const float* sb  = (const float*)d_in[0];
    const float* wts = (const float*)d_in[1];
    const float* hw  = (const float*)d_in[2];
    const float* hb  = (const float*)d_in[3];
    float* out = (float*)d_out;
    Gate32* tbl  = (Gate32*)d_ws;                       // 96*16 = 1536 B
    float2* cols = (float2*)((char*)d_ws + 4096);       // 128 KB
    const int B = in_sizes[0] / 8;                      // (B,8) state_batch
    coeff_kernel <<<1, 128, 0, stream>>>(wts, tbl);
    sim_kernel   <<<4, 64, 67072, stream>>>(tbl, cols);
    finish_kernel<<<(B + 255)/256, 256, 0, stream>>>(sb, cols, hw, hb, out, B);
}

// Round 8
// 93.904 us; speedup vs baseline: 1.2970x; 1.2970x over previous
//
#include <hip/hip_runtime.h>
#include <hip/hip_fp16.h>

// ---------------------------------------------------------------------------
// ROUND 15: R14's dense-MFMA sim (math VERIFIED: absmax 9.77e-4) was run at
// 1 wave/CU -> pure latency bound (76us; every ds_read ~120cy and 8-deep
// MFMA chain exposed). This round: SAME math, SAME addressing, distributed
// across 4 waves x 256 threads per block (4 blocks, 1 column each):
//   phase A (wave 0):  8x8 Kronecker factor build            -> barrier
//   phase B (all):     L/R row build, split (row,side,hk-half) -> barrier
//   phase C (wave w):  step1 tile (mt,nt) = (w>>1, w&1)       -> barrier
//   phase D (wave w):  step2 unit (nt2,mt2) = (w>>1, w&1)     -> barrier
// Same per-layer dataflow ordering as the serial version (each arrow above
// was a program-order dependency; now a barrier). DS issue from 4 waves
// interleaves on the LDS pipe; MFMA chains spread over 4 SIMDs.
// Math recap (verified R14): S[m][n], m=wires0-5, n=wires6-11;
//   S' = P_cnot(L S R^T); P_cnot folds into addressing:
//   U1 = S.R'^T (R' = gray6-rows of R); U2[k][n] = U1[k][n^63];
//   step2 transposed: W_x[n][m] = sum_k U_x^T[n][k] L[g6(m)][k];
//   S'[m][n] = W1 for even m, W2 for odd m (parity = lane lo5 bit 0).
// mfma_f32_32x32x16_f16; A: row=lane&31, k=8*(lane>>5)+i; B: col=lane&31;
// C/D: col=lane&31, row=(reg&3)+8*(reg>>2)+4*(lane>>5)  [HW m74/m101].
// f16 planes XOR-swizzled per 16B unit (unit ^= row&7).
// coeff_kernel / finish_kernel: verified R8+ unchanged.
// ---------------------------------------------------------------------------

typedef __half2 h2;
typedef _Float16 f16;
typedef __attribute__((ext_vector_type(8))) _Float16 f16x8;
typedef __attribute__((ext_vector_type(16))) float f32x16;

struct Gate32 { float a, b, c, d; };

#define SGN2 0x80008000
#define Z16 f32x16{0,0,0,0,0,0,0,0,0,0,0,0,0,0,0,0}

__device__ __forceinline__ float bpermf(int addr4, float v) {
    return __int_as_float(__builtin_amdgcn_ds_bpermute(addr4, __float_as_int(v)));
}
__device__ __forceinline__ int bci(h2 v)  { return __builtin_bit_cast(int, v); }
__device__ __forceinline__ h2 bch2(int v) { return __builtin_bit_cast(h2, v); }
__device__ __forceinline__ int g6(int x)  { return (x ^ (x >> 1)) & 63; }
__device__ __forceinline__ int moff(int row, int unit) {       // byte off in
    return row * 128 + ((unit ^ (row & 7)) << 4);              // f16[64][64]
}
__device__ __forceinline__ f16x8 fneg8(f16x8 v) {
    int4 x = __builtin_bit_cast(int4, v);
    x.x ^= SGN2; x.y ^= SGN2; x.z ^= SGN2; x.w ^= SGN2;
    return __builtin_bit_cast(f16x8, x);
}
__device__ __forceinline__ f32x16 MFMA(f16x8 a, f16x8 b, f32x16 c) {
    return __builtin_amdgcn_mfma_f32_32x32x16_f16(a, b, c, 0, 0, 0);
}

struct C2 { float r, i; };
__device__ __forceinline__ C2 cmul(C2 x, C2 y) {
    return { x.r*y.r - x.i*y.i, x.r*y.i + x.i*y.r };
}
// Rot entry (bi,bj): [[A-iB, -C-iD],[C-iD, A+iB]]
__device__ __forceinline__ C2 gent(const Gate32 g, int bi, int bj) {
    const float re = (bi == bj) ? g.a : (bi ? g.c : -g.c);
    const float im = (bi == bj) ? (bi ? g.b : -g.b) : -g.d;
    return { re, im };
}

// ---- kernel 0: gate coefficient table (R8-verified) -----------------------
__global__ void coeff_kernel(const float* __restrict__ wts, Gate32* __restrict__ tbl) {
    const int g = threadIdx.x;
    if (g >= 96) return;
    const int l = g / 12, w = g % 12;
    const float* lw = wts + l*36 + w*3;
    float ch, sh, ca, sa, cb, sb;
    __sincosf(0.5f*lw[1],           &sh, &ch);
    __sincosf(0.5f*(lw[0]+lw[2]),   &sa, &ca);
    __sincosf(0.5f*(lw[0]-lw[2]),   &sb, &cb);
    Gate32 r; r.a = ca*ch; r.b = sa*ch; r.c = cb*sh; r.d = sb*sh;
    tbl[g] = r;
}

// ---- kernel 1: 4 blocks x 4 waves, dense MFMA column sim ------------------
__global__ __launch_bounds__(256, 1)
void sim_kernel(const Gate32* __restrict__ tbl, float2* __restrict__ cols) {
    extern __shared__ char smem[];
    char* Lr = smem;                 // f16[64][64] planes, unit-swizzled
    char* Li = smem + 8192;
    char* Rr = smem + 16384;
    char* Ri = smem + 24576;
    char* Sr = smem + 32768;         // state planes (row-major [m][n])
    char* Si = smem + 40960;
    char* Ur = smem + 49152;         // U^T planes (row-major [n][m])
    char* Ui = smem + 57344;
    float* KLr = (float*)(smem + 65536);   // 8x8 factor matrices
    float* KLi = KLr + 64;  float* KRr = KLr + 128; float* KRi = KLr + 192;
    f16* KLpr = (f16*)(KLr + 256);
    f16* KLpi = KLpr + 64;  f16* KRpr = KLpr + 128; f16* KRpi = KLpr + 192;

    const int tid  = threadIdx.x;
    const int lane = tid & 63;
    const int wid  = tid >> 6;
    const int b    = blockIdx.x;
    const int lo5  = lane & 31, hi = (lane >> 5) & 1;

    // ---- init S = delta(m = 16b, n = 0) ----
    {
        const int4 z = make_int4(0, 0, 0, 0);
#pragma unroll
        for (int u = 0; u < 2; ++u) {
            const int idx = u * 256 + tid;          // 512 units per plane
            const int row = idx >> 3, un = idx & 7;
            *(int4*)(Sr + moff(row, un)) = z;
            *(int4*)(Si + moff(row, un)) = z;
        }
    }
    __syncthreads();
    if (tid == 0) {
        const int row = 16 * b;
        *(f16*)(Sr + moff(row, 0)) = (f16)1.0f;     // element (row, col 0)
    }
    __syncthreads();

#pragma unroll 1
    for (int l = 0; l < 8; ++l) {
        const Gate32* gl = tbl + l * 12;
        // ---- phase A (wave 0): 8x8 Kronecker halves, lane = (ip,jp) ----
        if (tid < 64) {
            const int ip = tid >> 3, jp = tid & 7;
            const int i2 = (ip>>2)&1, i1 = (ip>>1)&1, i0 = ip&1;
            const int j2 = (jp>>2)&1, j1 = (jp>>1)&1, j0 = jp&1;
            const C2 kl  = cmul(cmul(gent(gl[0],i2,j2), gent(gl[1],i1,j1)), gent(gl[2],i0,j0));
            const C2 klp = cmul(cmul(gent(gl[3],i2,j2), gent(gl[4],i1,j1)), gent(gl[5],i0,j0));
            const C2 kr  = cmul(cmul(gent(gl[6],i2,j2), gent(gl[7],i1,j1)), gent(gl[8],i0,j0));
            const C2 krp = cmul(cmul(gent(gl[9],i2,j2), gent(gl[10],i1,j1)), gent(gl[11],i0,j0));
            KLr[tid] = kl.r;  KLi[tid] = kl.i;
            KRr[tid] = kr.r;  KRi[tid] = kr.i;
            KLpr[tid] = (f16)klp.r;  KLpi[tid] = (f16)klp.i;
            KRpr[tid] = (f16)krp.r;  KRpi[tid] = (f16)krp.i;
        }
        __syncthreads();
        // ---- phase B (all): row build. thread = (row, side, hk-half) ----
        {
            const int r = tid & 63, rh = r >> 3, rl = r & 7;
            const int side = (tid >> 6) & 1;        // 0 = L, 1 = R
            const int hsel = tid >> 7;              // hk 0-3 or 4-7
            const float* xr4 = side ? (KRr + rh*8) : (KLr + rh*8);
            const float* xi4 = side ? (KRi + rh*8) : (KLi + rh*8);
            const int4 pyr = *(const int4*)((side ? KRpr : KLpr) + rl*8);
            const int4 pyi = *(const int4*)((side ? KRpi : KLpi) + rl*8);
            const h2 yr[4] = { bch2(pyr.x), bch2(pyr.y), bch2(pyr.z), bch2(pyr.w) };
            const h2 yi[4] = { bch2(pyi.x), bch2(pyi.y), bch2(pyi.z), bch2(pyi.w) };
            char* Pr = side ? Rr : Lr;
            char* Pi = side ? Ri : Li;
#pragma unroll
            for (int q = 0; q < 4; ++q) {
                const int hk = 4*hsel + q;
                const h2 xr2  = __float2half2_rn(xr4[hk]);
                const h2 xi2  = __float2half2_rn(xi4[hk]);
                const h2 nxi2 = bch2(bci(xi2) ^ SGN2);
                h2 oR[4], oI[4];
#pragma unroll
                for (int t = 0; t < 4; ++t) {
                    oR[t] = __hfma2(nxi2, yi[t], __hmul2(xr2, yr[t]));
                    oI[t] = __hfma2(xi2,  yr[t], __hmul2(xr2, yi[t]));
                }
                *(int4*)(Pr + moff(r, hk)) = make_int4(bci(oR[0]), bci(oR[1]), bci(oR[2]), bci(oR[3]));
                *(int4*)(Pi + moff(r, hk)) = make_int4(bci(oI[0]), bci(oI[1]), bci(oI[2]), bci(oI[3]));
            }
        }
        __syncthreads();
        // ---- phase C (wave wid): step1 tile (mt,nt) = (wid>>1, wid&1) ----
        {
            const int mt = wid >> 1, nt = wid & 1;
            f16x8 asr[4], asi[4], brr[4], bri[4];
            const int arow = 32*mt + lo5;
            const int brow = g6(32*nt + lo5);
#pragma unroll
            for (int kc = 0; kc < 4; ++kc) {
                const int un = 2*kc + hi;
                asr[kc] = *(const f16x8*)(Sr + moff(arow, un));
                asi[kc] = *(const f16x8*)(Si + moff(arow, un));
                brr[kc] = *(const f16x8*)(Rr + moff(brow, un));
                bri[kc] = *(const f16x8*)(Ri + moff(brow, un));
            }
            f32x16 ur = Z16, ui = Z16;
#pragma unroll
            for (int kc = 0; kc < 4; ++kc) {
                const f16x8 nri = fneg8(bri[kc]);
                ur = MFMA(asr[kc], brr[kc], ur);   // Ur = Sr.Rr^T - Si.Ri^T
                ur = MFMA(asi[kc], nri,     ur);
                ui = MFMA(asr[kc], bri[kc], ui);   // Ui = Sr.Ri^T + Si.Rr^T
                ui = MFMA(asi[kc], brr[kc], ui);
            }
            // write U^T[n][m]: lane col n, 4-runs of consecutive m
            const int urow = 32*nt + lo5;
#pragma unroll
            for (int gg = 0; gg < 4; ++gg) {
                const h2 p0 = __floats2half2_rn(ur[4*gg+0], ur[4*gg+1]);
                const h2 p1 = __floats2half2_rn(ur[4*gg+2], ur[4*gg+3]);
                *(int2*)(Ur + moff(urow, 4*mt+gg) + 8*hi) = make_int2(bci(p0), bci(p1));
                const h2 q0 = __floats2half2_rn(ui[4*gg+0], ui[4*gg+1]);
                const h2 q1 = __floats2half2_rn(ui[4*gg+2], ui[4*gg+3]);
                *(int2*)(Ui + moff(urow, 4*mt+gg) + 8*hi) = make_int2(bci(q0), bci(q1));
            }
        }
        __syncthreads();
        // ---- phase D (wave wid): step2 unit (nt2,mt2) = (wid>>1, wid&1) ----
        {
            const int nt2 = wid >> 1, mt2 = wid & 1;
            f16x8 a1r[4], a1i[4], a2r[4], a2i[4];
            const int r1 = 32*nt2 + lo5, r2 = r1 ^ 63;   // U2 = row-flip read
#pragma unroll
            for (int kc = 0; kc < 4; ++kc) {
                const int un = 2*kc + hi;
                a1r[kc] = *(const f16x8*)(Ur + moff(r1, un));
                a1i[kc] = *(const f16x8*)(Ui + moff(r1, un));
                a2r[kc] = *(const f16x8*)(Ur + moff(r2, un));
                a2i[kc] = *(const f16x8*)(Ui + moff(r2, un));
            }
            const int m = 32*mt2 + lo5;
            const int lrow = g6(m);                      // folded row-gray
            f16x8 blr[4], bli[4];
#pragma unroll
            for (int kc = 0; kc < 4; ++kc) {
                const int un = 2*kc + hi;
                blr[kc] = *(const f16x8*)(Lr + moff(lrow, un));
                bli[kc] = *(const f16x8*)(Li + moff(lrow, un));
            }
            f32x16 w1r = Z16, w1i = Z16, w2r = Z16, w2i = Z16;
#pragma unroll
            for (int kc = 0; kc < 4; ++kc) {
                const f16x8 nbli = fneg8(bli[kc]);
                w1r = MFMA(a1r[kc], blr[kc], w1r);
                w1r = MFMA(a1i[kc], nbli,    w1r);
                w1i = MFMA(a1r[kc], bli[kc], w1i);
                w1i = MFMA(a1i[kc], blr[kc], w1i);
                w2r = MFMA(a2r[kc], blr[kc], w2r);
                w2r = MFMA(a2i[kc], nbli,    w2r);
                w2i = MFMA(a2r[kc], bli[kc], w2i);
                w2i = MFMA(a2i[kc], blr[kc], w2i);
            }
            const bool odd = (m & 1);
            if (l < 7) {                                 // S'[m][n] row-major
#pragma unroll
                for (int gg = 0; gg < 4; ++gg) {
                    float s0 = odd ? w2r[4*gg+0] : w1r[4*gg+0];
                    float s1 = odd ? w2r[4*gg+1] : w1r[4*gg+1];
                    float s2 = odd ? w2r[4*gg+2] : w1r[4*gg+2];
                    float s3 = odd ? w2r[4*gg+3] : w1r[4*gg+3];
                    *(int2*)(Sr + moff(m, 4*nt2+gg) + 8*hi) =
                        make_int2(bci(__floats2half2_rn(s0, s1)),
                                  bci(__floats2half2_rn(s2, s3)));
                    s0 = odd ? w2i[4*gg+0] : w1i[4*gg+0];
                    s1 = odd ? w2i[4*gg+1] : w1i[4*gg+1];
                    s2 = odd ? w2i[4*gg+2] : w1i[4*gg+2];
                    s3 = odd ? w2i[4*gg+3] : w1i[4*gg+3];
                    *(int2*)(Si + moff(m, 4*nt2+gg) + 8*hi) =
                        make_int2(bci(__floats2half2_rn(s0, s1)),
                                  bci(__floats2half2_rn(s2, s3)));
                }
            } else {                                     // final: f32 global
#pragma unroll
                for (int gg = 0; gg < 4; ++gg)
#pragma unroll
                for (int e = 0; e < 4; ++e) {
                    const int n = 32*nt2 + 8*gg + 4*hi + e;
                    const int r = 4*gg + e;
                    const float vr = odd ? w2r[r] : w1r[r];
                    const float vi = odd ? w2i[r] : w1i[r];
                    cols[b*4096 + (m << 6) + n] = make_float2(vr, vi);
                }
            }
        }
        __syncthreads();
    }
}

// ---- kernel 2: redundant G-reduce per block + per-sample quadratic form ---
__global__ __launch_bounds__(256)
void finish_kernel(const float* __restrict__ sb,
                   const float2* __restrict__ cols,
                   const float* __restrict__ hw,
                   const float* __restrict__ hb,
                   float* __restrict__ out, int B) {
    const int tid  = threadIdx.x;
    const int lane = tid & 63, wid = tid >> 6;

    float hwv[12];
#pragma unroll
    for (int w = 0; w < 12; ++w) hwv[w] = hw[w];

    float Klo = 0.f;
#pragma unroll
    for (int w = 4; w < 12; ++w)
        Klo += ((tid >> (11 - w)) & 1) ? -hwv[w] : hwv[w];

    float g[10];
#pragma unroll
    for (int m = 0; m < 10; ++m) g[m] = 0.f;

#pragma unroll 1
    for (int it = 0; it < 16; ++it) {
        const int q = (it << 8) | tid;
        const float2 c0 = cols[q];
        const float2 c1 = cols[4096  + q];
        const float2 c2 = cols[8192  + q];
        const float2 c3 = cols[12288 + q];
        float K = Klo;
#pragma unroll
        for (int w = 0; w < 4; ++w)
            K += ((it >> (3 - w)) & 1) ? -hwv[w] : hwv[w];
        g[0] += K * (c0.x*c0.x + c0.y*c0.y);
        g[1] += K * (c1.x*c1.x + c1.y*c1.y);
        g[2] += K * (c2.x*c2.x + c2.y*c2.y);
        g[3] += K * (c3.x*c3.x + c3.y*c3.y);
        g[4] += K * (c0.x*c1.x + c0.y*c1.y);
        g[5] += K * (c2.x*c3.x + c2.y*c3.y);
        g[6] += K * (c0.x*c2.y - c0.y*c2.x);
        g[7] += K * (c0.x*c3.y - c0.y*c3.x);
        g[8] += K * (c1.x*c2.y - c1.y*c2.x);
        g[9] += K * (c1.x*c3.y - c1.y*c3.x);
    }

    __shared__ float gsh[4][10];
#pragma unroll
    for (int m = 0; m < 10; ++m) {
#pragma unroll
        for (int off = 1; off < 64; off <<= 1)
            g[m] += bpermf((lane ^ off) << 2, g[m]);
    }
    if (lane == 0) {
#pragma unroll
        for (int m = 0; m < 10; ++m) gsh[wid][m] = g[m];
    }
    __syncthreads();
    float G[10];
#pragma unroll
    for (int m = 0; m < 10; ++m) {
        const float s = gsh[0][m] + gsh[1][m] + gsh[2][m] + gsh[3][m];
        G[m] = (m < 4) ? s : 2.f * s;
    }

    const int i = blockIdx.x * 256 + tid;
    if (i < B) {
        const float2 x = *reinterpret_cast<const float2*>(sb + i*8);
        float c0, s0, c1, s1;
        __sincosf(0.5f * x.x, &s0, &c0);
        __sincosf(0.5f * x.y, &s1, &c1);
        const float a0 = c0*c1, a1 = c0*s1, a2 = s0*c1, a3 = s0*s1;
        const float r = G[0]*a0*a0 + G[1]*a1*a1 + G[2]*a2*a2 + G[3]*a3*a3
                      + G[4]*(a0*a1) + G[5]*(a2*a3)
                      + G[6]*(a0*a2) + G[7]*(a0*a3)
                      + G[8]*(a1*a2) + G[9]*(a1*a3);
        out[i] = r + hb[0];
    }
}

extern "C" void kernel_launch(void* const* d_in, const int* in_sizes, int n_in,
                              void* d_out, int out_size, void* d_ws, size_t ws_size,
                              hipStream_t stream) {
    const float* sb  = (const float*)d_in[0];
    const float* wts = (const float*)d_in[1];
    const float* hw  = (const float*)d_in[2];
    const float* hb  = (const float*)d_in[3];
    float* out = (float*)d_out;
    Gate32* tbl  = (Gate32*)d_ws;                       // 96*16 = 1536 B
    float2* cols = (float2*)((char*)d_ws + 4096);       // 128 KB
    const int B = in_sizes[0] / 8;                      // (B,8) state_batch
    coeff_kernel <<<1, 128, 0, stream>>>(wts, tbl);
    sim_kernel   <<<4, 256, 67072, stream>>>(tbl, cols);
    finish_kernel<<<(B + 255)/256, 256, 0, stream>>>(sb, cols, hw, hb, out, B);
}